// Round 18
// baseline (269.197 us; speedup 1.0000x reference)
//
#include <hip/hip_runtime.h>
#include <stdint.h>

#define DEVI static __device__ __forceinline__

typedef __attribute__((ext_vector_type(4))) float f32x4;
typedef __attribute__((ext_vector_type(16))) float f32x16;
typedef __attribute__((ext_vector_type(8))) __bf16 bf16x8;
typedef __attribute__((ext_vector_type(4))) uint16_t u16x4;
typedef uint16_t u16;

// ---------- helpers ----------
DEVI u16 f2bf(float f) {  // round-to-nearest-even fp32 -> bf16
  union { float f; uint32_t u; } v; v.f = f;
  uint32_t r = v.u + 0x7FFFu + ((v.u >> 16) & 1u);
  return (u16)(r >> 16);
}

DEVI f32x4 mfma16(bf16x8 a, bf16x8 b, f32x4 c) {
  return __builtin_amdgcn_mfma_f32_16x16x32_bf16(a, b, c, 0, 0, 0);
}

DEVI f32x16 mfma32(bf16x8 a, bf16x8 b, f32x16 c) {
  return __builtin_amdgcn_mfma_f32_32x32x16_bf16(a, b, c, 0, 0, 0);
}

DEVI void load_lds16(const void* g, void* l) {  // async global->LDS, 16B/lane
  __builtin_amdgcn_global_load_lds(
      (const __attribute__((address_space(1))) void*)g,
      (__attribute__((address_space(3))) void*)l, 16, 0, 0);
}

DEVI bf16x8 lds_frag(const u16* p) { return *(const bf16x8*)p; }

DEVI f32x16 zero16() {
  f32x16 z;
#pragma unroll
  for (int i = 0; i < 16; ++i) z[i] = 0.f;
  return z;
}

// hardware exp2 (1 instruction)
DEVI float exp2_hw(float x) {
  float r;
  asm("v_exp_f32 %0, %1" : "=v"(r) : "v"(x));
  return r;
}

// pack 2 f32 -> bf16x2 word in ONE instruction (RNE)
DEVI uint32_t cvtpk(float lo, float hi) {
  uint32_t r;
  asm("v_cvt_pk_bf16_f32 %0, %1, %2" : "=v"(r) : "v"(lo), "v"(hi));
  return r;
}

// 8 fp32 (two f32x4) -> bf16x8 via 4 cvt_pk
DEVI bf16x8 cvt8v(f32x4 lo, f32x4 hi) {
  union { uint32_t u[4]; bf16x8 v; } c;
  c.u[0] = cvtpk(lo[0], lo[1]);
  c.u[1] = cvtpk(lo[2], lo[3]);
  c.u[2] = cvtpk(hi[0], hi[1]);
  c.u[3] = cvtpk(hi[2], hi[3]);
  return c.v;
}

// 3-input max in one instruction (T17)
DEVI float max3f(float a, float b, float c) {
  float r;
  asm("v_max3_f32 %0, %1, %2, %3" : "=v"(r) : "v"(a), "v"(b), "v"(c));
  return r;
}

// cross-half exchange via shfl (for scalar reduces; coalescing-proof)
DEVI float partner_f(float x) { return __shfl_xor(x, 32, 64); }

// REAL v_permlane32_swap_b32: exchanges a.hi-lanes <-> b.lo-lanes.
// ONLY safe when a and b hold DISTINCT values (same-value operands may be
// register-coalesced -> swap-with-self; that was the round-3 bug).
DEVI void pswap_asm(uint32_t& a, uint32_t& b) {
  asm("v_permlane32_swap_b32 %0, %1" : "+v"(a), "+v"(b));
}

// ---------- fp32 -> bf16 conversion (WEIGHTS ONLY) ----------
#define NBIG (4 * 2048 * 1024)
#define NW (1024 * 1024)

__global__ __launch_bounds__(256) void cvt_kernel(const float* Wq,
                                                  const float* Wk,
                                                  const float* Wv,
                                                  const float* Wo, u16* Wqb,
                                                  u16* Wkb, u16* Wvb,
                                                  u16* Wob) {
  const float* src;
  u16* dst;
  switch (blockIdx.y) {
    case 0: src = Wq; dst = Wqb; break;
    case 1: src = Wk; dst = Wkb; break;
    case 2: src = Wv; dst = Wvb; break;
    default: src = Wo; dst = Wob; break;
  }
  int i = (blockIdx.x * 256 + threadIdx.x) * 4;
  if (i >= NW) return;
  float4 f = *(const float4*)&src[i];
  u16x4 o;
  o.x = f2bf(f.x); o.y = f2bf(f.y); o.z = f2bf(f.z); o.w = f2bf(f.w);
  *(u16x4*)&dst[i] = o;
}

// ---------- QKV projection: BK=64 (16 drain-bound steps instead of 32) ------
// fp32 A staged via global_load_lds (32 KB/step), bf16 B (16 KB/step); double-
// buffered (96 KB LDS, 1 block/CU). Swizzles (both-sides, rule 21):
//   A rows = 256 B: 16B-granule ^= row&15 (read <=4-way conflict)
//   B rows = 128 B: 16B-granule ^= row&7  (8-way, as before)
// Per-CU model: 6 rounds x 16 steps x ~1450cy ~= 62us (vs 32-step ~100us).
__global__ __launch_bounds__(256) void proj_kernel(
    const float* qx, const float* kx, const float* vx, const u16* Wq,
    const u16* Wk, const u16* Wv, const float* bq, const float* bk,
    const float* bv, u16* Qn, u16* Kn, u16* Vt) {
  __shared__ __align__(16) float Af[2][128 * 64];  // 64 KB
  __shared__ __align__(16) u16 Bs2[2][128 * 64];   // 32 KB

  const int z = blockIdx.z;
  const float* A32 = z == 0 ? qx : z == 1 ? kx : vx;
  const u16* W = z == 0 ? Wq : z == 1 ? Wk : Wv;
  const float* bias = z == 0 ? bq : z == 1 ? bk : bv;
  const int bm = blockIdx.x, bn = blockIdx.y;

  const int tid = threadIdx.x;
  const int w = tid >> 6, l = tid & 63;
  const int lr = l & 15, lg = l >> 4;
  const int wr = (w >> 1) * 64, wc = (w & 1) * 64;

  // ---- A staging: 32 chunks of 1KB (4 rows x 64 fp32); wave w: 8w..8w+7.
  //      lane l -> within-chunk row l>>4, granule l&15; source pre-swizzled.
  const float* gA[8];
  int laoff[8];
#pragma unroll
  for (int i = 0; i < 8; ++i) {
    const int c = 8 * w + i;
    const int row = c * 4 + (l >> 4);                 // tile row 0..127
    const int gsw = (l & 15) ^ (row & 15);            // swizzled source granule
    gA[i] = A32 + (size_t)(bm * 128 + row) * 1024 + gsw * 4;
    laoff[i] = c * 256;  // fp32 units
  }
  // ---- B staging: 16 chunks of 1KB (8 rows x 64 bf16); wave w: 4w..4w+3.
  const u16* gB[4];
  int lboff[4];
#pragma unroll
  for (int i = 0; i < 4; ++i) {
    const int c = 4 * w + i;
    const int row = c * 8 + (l >> 3);
    const int gsw = (l & 7) ^ (row & 7);
    gB[i] = W + (size_t)(bn * 128 + row) * 1024 + gsw * 8;
    lboff[i] = c * 512;  // u16 units
  }

  // ---- read offsets ----
  // A frag (mi, ks, j): row = wr+mi*16+lr; granule = ks*8+lg*2+j, ^ (lr&15)
  int aoff[4][2][2];
#pragma unroll
  for (int mi = 0; mi < 4; ++mi)
#pragma unroll
    for (int ks = 0; ks < 2; ++ks)
#pragma unroll
      for (int j = 0; j < 2; ++j) {
        const int row = wr + mi * 16 + lr;
        aoff[mi][ks][j] = row * 64 + ((ks * 8 + lg * 2 + j) ^ (row & 15)) * 4;
      }
  // B frag (nj, ks): row = wc+nj*16+lr; granule = ks*4+lg, ^ (row&7)
  int boff[4][2];
#pragma unroll
  for (int nj = 0; nj < 4; ++nj)
#pragma unroll
    for (int ks = 0; ks < 2; ++ks) {
      const int row = wc + nj * 16 + lr;
      boff[nj][ks] = row * 64 + ((ks * 4 + lg) ^ (row & 7)) * 8;
    }

  f32x4 acc[4][4];
#pragma unroll
  for (int i = 0; i < 4; ++i)
#pragma unroll
    for (int j = 0; j < 4; ++j) acc[i][j] = (f32x4){0.f, 0.f, 0.f, 0.f};

  // prologue: stage tile 0 -> buf 0 (12 loads/wave)
#pragma unroll
  for (int i = 0; i < 8; ++i) load_lds16(gA[i], &Af[0][laoff[i]]);
#pragma unroll
  for (int i = 0; i < 4; ++i) load_lds16(gB[i], &Bs2[0][lboff[i]]);
  __syncthreads();

  int cur = 0;
  for (int k0 = 0; k0 < 1024; k0 += 64) {
    const int nxt = cur ^ 1;
    if (k0 + 64 < 1024) {
#pragma unroll
      for (int i = 0; i < 8; ++i)
        load_lds16(gA[i] + k0 + 64, &Af[nxt][laoff[i]]);
#pragma unroll
      for (int i = 0; i < 4; ++i)
        load_lds16(gB[i] + k0 + 64, &Bs2[nxt][lboff[i]]);
    }
    const float* Ac = Af[cur];
    const u16* Bc = Bs2[cur];
    bf16x8 af[4][2], bff[4][2];
#pragma unroll
    for (int mi = 0; mi < 4; ++mi)
#pragma unroll
      for (int ks = 0; ks < 2; ++ks) {
        const f32x4 lo = *(const f32x4*)&Ac[aoff[mi][ks][0]];
        const f32x4 hi = *(const f32x4*)&Ac[aoff[mi][ks][1]];
        af[mi][ks] = cvt8v(lo, hi);
      }
#pragma unroll
    for (int nj = 0; nj < 4; ++nj)
#pragma unroll
      for (int ks = 0; ks < 2; ++ks) bff[nj][ks] = lds_frag(&Bc[boff[nj][ks]]);
#pragma unroll
    for (int ks = 0; ks < 2; ++ks)
#pragma unroll
      for (int mi = 0; mi < 4; ++mi)
#pragma unroll
        for (int nj = 0; nj < 4; ++nj)
          acc[mi][nj] = mfma16(af[mi][ks], bff[nj][ks], acc[mi][nj]);
    __syncthreads();
    cur = nxt;
  }

  // ---- epilogue: Q/K natural coalesced; V transposed scatter ----
#pragma unroll
  for (int nj = 0; nj < 4; ++nj) {
    const int col = bn * 128 + wc + nj * 16 + lr;
    const float bb = bias[col];
#pragma unroll
    for (int mi = 0; mi < 4; ++mi) {
      const int m0 = bm * 128 + wr + mi * 16 + lg * 4;
      if (z < 2) {
        u16* dst = (z == 0) ? Qn : Kn;
#pragma unroll
        for (int r = 0; r < 4; ++r)
          dst[(size_t)(m0 + r) * 1024 + col] = f2bf(acc[mi][nj][r] + bb);
      } else {
        const int b = m0 >> 11;
        const int s0 = m0 & 2047;
        const int h = col >> 6, d = col & 63;
        u16x4 pk;
        pk.x = f2bf(acc[mi][nj][0] + bb);
        pk.y = f2bf(acc[mi][nj][1] + bb);
        pk.z = f2bf(acc[mi][nj][2] + bb);
        pk.w = f2bf(acc[mi][nj][3] + bb);
        *(u16x4*)&Vt[(((size_t)(b * 16 + h) * 64) + d) * 2048 + s0] = pk;
      }
    }
  }
}

// ---------- GEMM core: single-barrier double-buffered (r10, proven) ---------
DEVI void gemm_core_1024_db(const u16* __restrict__ A,
                            const u16* __restrict__ Bm, int bm, int bn,
                            u16* As, u16* Bs, f32x4 acc[4][4]) {
  const int tid = threadIdx.x;
  const int w = tid >> 6, l = tid & 63;
  const int lr = l & 15, lg = l >> 4;
  const int wr = (w >> 1) * 64, wc = (w & 1) * 64;

  for (int i = 0; i < 4; ++i)
    for (int j = 0; j < 4; ++j) acc[i][j] = (f32x4){0.f, 0.f, 0.f, 0.f};

  const int c0 = 2 * w, c1 = 2 * w + 1;
  const u16* gA0 = A + (size_t)(bm * 128 + c0 * 16 + (l >> 2)) * 1024 + (l & 3) * 8;
  const u16* gA1 = A + (size_t)(bm * 128 + c1 * 16 + (l >> 2)) * 1024 + (l & 3) * 8;
  const u16* gB0 = Bm + (size_t)(bn * 128 + c0 * 16 + (l >> 2)) * 1024 + (l & 3) * 8;
  const u16* gB1 = Bm + (size_t)(bn * 128 + c1 * 16 + (l >> 2)) * 1024 + (l & 3) * 8;
  const int sA0 = c0 * 512, sA1 = c1 * 512;

  int aoff[4], boff[4];
#pragma unroll
  for (int mi = 0; mi < 4; ++mi) aoff[mi] = (wr + mi * 16 + lr) * 32 + lg * 8;
#pragma unroll
  for (int nj = 0; nj < 4; ++nj) boff[nj] = (wc + nj * 16 + lr) * 32 + lg * 8;

  load_lds16(gA0, As + sA0);
  load_lds16(gA1, As + sA1);
  load_lds16(gB0, Bs + sA0);
  load_lds16(gB1, Bs + sA1);
  __syncthreads();

  int cur = 0;
  for (int k0 = 0; k0 < 1024; k0 += 32) {
    const int nxt = cur ^ 1;
    if (k0 + 32 < 1024) {
      load_lds16(gA0 + k0 + 32, As + nxt * 4096 + sA0);
      load_lds16(gA1 + k0 + 32, As + nxt * 4096 + sA1);
      load_lds16(gB0 + k0 + 32, Bs + nxt * 4096 + sA0);
      load_lds16(gB1 + k0 + 32, Bs + nxt * 4096 + sA1);
    }
    const u16* Ac = As + cur * 4096;
    const u16* Bc = Bs + cur * 4096;
    bf16x8 af[4], bff[4];
#pragma unroll
    for (int mi = 0; mi < 4; ++mi) af[mi] = lds_frag(&Ac[aoff[mi]]);
#pragma unroll
    for (int nj = 0; nj < 4; ++nj) bff[nj] = lds_frag(&Bc[boff[nj]]);
#pragma unroll
    for (int mi = 0; mi < 4; ++mi)
#pragma unroll
      for (int nj = 0; nj < 4; ++nj)
        acc[mi][nj] = mfma16(af[mi], bff[nj], acc[mi][nj]);
    __syncthreads();
    cur = nxt;
  }
}

// ---------- output projection ----------
__global__ __launch_bounds__(256) void outproj_kernel(const u16* O,
                                                      const u16* Wo,
                                                      const float* bo,
                                                      float* out) {
  __shared__ __align__(16) u16 As[2 * 128 * 32];
  __shared__ __align__(16) u16 Bs[2 * 128 * 32];
  f32x4 acc[4][4];
  gemm_core_1024_db(O, Wo, blockIdx.x, blockIdx.y, As, Bs, acc);

  const int tid = threadIdx.x;
  const int w = tid >> 6, l = tid & 63;
  const int lr = l & 15, lg = l >> 4;
  const int wr = (w >> 1) * 64, wc = (w & 1) * 64;
#pragma unroll
  for (int nj = 0; nj < 4; ++nj) {
    const int col = blockIdx.y * 128 + wc + nj * 16 + lr;
    const float bb = bo[col];
#pragma unroll
    for (int mi = 0; mi < 4; ++mi) {
      const int m0 = blockIdx.x * 128 + wr + mi * 16 + lg * 4;
#pragma unroll
      for (int r = 0; r < 4; ++r)
        out[(size_t)(m0 + r) * 1024 + col] = acc[mi][nj][r] + bb;
    }
  }
}

// ---------- flash attention v7n (r17 version, unchanged) --------------------
#define LDPK 72
#define NT 32  // 2048 / 64
__global__ __launch_bounds__(512) void attn_kernel(const u16* Qn, const u16* Kn,
                                                   const u16* Vt, u16* Ob) {
  __shared__ __align__(16) u16 Kl[2][64 * LDPK];
  __shared__ __align__(16) u16 Vl[2][64 * LDPK];

  const int tid = threadIdx.x, w = tid >> 6, l = tid & 63;
  const int q = l & 31, hi = l >> 5;
  const int bh = blockIdx.y;
  const int b2 = bh >> 4, h = bh & 15;
  const int q0 = blockIdx.x * 256 + w * 32;
  const u16* Qh = Qn + (size_t)b2 * 2048 * 1024 + h * 64;
  const u16* Kh = Kn + (size_t)b2 * 2048 * 1024 + h * 64;
  const u16* Vh = Vt + (size_t)bh * 64 * 2048;

  const float SC2 = 0.1803368801f;  // 0.125 * log2(e)

  bf16x8 qf[4];
#pragma unroll
  for (int ds = 0; ds < 4; ++ds)
    qf[ds] = *(const bf16x8*)&Qh[(size_t)(q0 + q) * 1024 + ds * 16 + hi * 8];

  f32x16 o0 = zero16(), o1 = zero16();
  float m = -1.0e30f, ln = 0.f;

  const int srow = tid >> 3, g0 = tid & 7;

  int koff[2][4], voff[2][4];
#pragma unroll
  for (int kb = 0; kb < 2; ++kb)
#pragma unroll
    for (int ds = 0; ds < 4; ++ds)
      koff[kb][ds] = (kb * 32 + q) * LDPK + ds * 16 + hi * 8;
#pragma unroll
  for (int db = 0; db < 2; ++db)
#pragma unroll
    for (int ks = 0; ks < 4; ++ks)
      voff[db][ks] = (db * 32 + q) * LDPK + ks * 16 + hi * 8;

  bf16x8 kv = *(const bf16x8*)&Kh[(size_t)srow * 1024 + g0 * 8];
  bf16x8 vv = *(const bf16x8*)&Vh[(size_t)srow * 2048 + g0 * 8];
  *(bf16x8*)&Kl[0][srow * LDPK + g0 * 8] = kv;
  *(bf16x8*)&Vl[0][srow * LDPK + g0 * 8] = vv;
  kv = *(const bf16x8*)&Kh[(size_t)(64 + srow) * 1024 + g0 * 8];
  vv = *(const bf16x8*)&Vh[(size_t)srow * 2048 + 64 + g0 * 8];
  const u16* gk = Kh + (size_t)(2 * 64 + srow) * 1024 + g0 * 8;
  const u16* gv = Vh + (size_t)srow * 2048 + 2 * 64 + g0 * 8;
  __syncthreads();

  for (int kt = 0; kt < NT; ++kt) {
    const int cur = kt & 1;
    const u16* Kc = Kl[cur];
    const u16* Vc = Vl[cur];

    f32x16 c0 = zero16(), c1 = zero16();
    __builtin_amdgcn_s_setprio(1);
#pragma unroll
    for (int ds = 0; ds < 4; ++ds)
      c0 = mfma32(lds_frag(&Kc[koff[0][ds]]), qf[ds], c0);
#pragma unroll
    for (int ds = 0; ds < 4; ++ds)
      c1 = mfma32(lds_frag(&Kc[koff[1][ds]]), qf[ds], c1);
    __builtin_amdgcn_s_setprio(0);

    float tm[16];
#pragma unroll
    for (int r = 0; r < 16; ++r) tm[r] = fmaxf(c0[r], c1[r]);
    {
      const float m0_ = max3f(tm[0], tm[1], tm[2]);
      const float m1_ = max3f(tm[3], tm[4], tm[5]);
      const float m2_ = max3f(tm[6], tm[7], tm[8]);
      const float m3_ = max3f(tm[9], tm[10], tm[11]);
      const float m4_ = max3f(tm[12], tm[13], tm[14]);
      const float a_ = max3f(m0_, m1_, m2_);
      const float b_ = max3f(m3_, m4_, tm[15]);
      tm[0] = fmaxf(a_, b_);
    }
    const float mx = fmaxf(tm[0], partner_f(tm[0]));
    if (!__all(mx - m <= 64.0f)) {
      const float mnew = fmaxf(m, mx);
      const float a = exp2_hw((m - mnew) * SC2);
      m = mnew;
#pragma unroll
      for (int r = 0; r < 16; ++r) { o0[r] *= a; o1[r] *= a; }
      ln *= a;
    }
    const float m2 = m * SC2;
    float p0[16], p1[16];
#pragma unroll
    for (int r = 0; r < 16; ++r) {
      p0[r] = exp2_hw(__builtin_fmaf(c0[r], SC2, -m2));
      p1[r] = exp2_hw(__builtin_fmaf(c1[r], SC2, -m2));
    }
    float ts[16];
#pragma unroll
    for (int r = 0; r < 16; ++r) ts[r] = p0[r] + p1[r];
#pragma unroll
    for (int s = 8; s > 0; s >>= 1)
#pragma unroll
      for (int r = 0; r < s; ++r) ts[r] += ts[r + s];
    ln += ts[0] + partner_f(ts[0]);

    if (kt + 1 < NT) {
      *(bf16x8*)&Kl[cur ^ 1][srow * LDPK + g0 * 8] = kv;
      *(bf16x8*)&Vl[cur ^ 1][srow * LDPK + g0 * 8] = vv;
    }
    if (kt + 2 < NT) {
      kv = *(const bf16x8*)gk;
      vv = *(const bf16x8*)gv;
      gk += 64 * 1024; gv += 64;
    }

    uint32_t wv[16];
#pragma unroll
    for (int i = 0; i < 8; ++i) {
      wv[i]     = cvtpk(p0[2 * i], p0[2 * i + 1]);
      wv[8 + i] = cvtpk(p1[2 * i], p1[2 * i + 1]);
    }
    bf16x8 pa[4];
#pragma unroll
    for (int ks = 0; ks < 4; ++ks) {
      const int base = (ks >> 1) * 8 + 4 * (ks & 1);
      uint32_t x0 = wv[base],     y0 = wv[base + 2];
      uint32_t x1 = wv[base + 1], y1 = wv[base + 3];
      pswap_asm(x0, y0);
      pswap_asm(x1, y1);
      union { uint32_t u[4]; bf16x8 v; } cvt;
      cvt.u[0] = x0; cvt.u[1] = x1; cvt.u[2] = y0; cvt.u[3] = y1;
      pa[ks] = cvt.v;
    }

    __builtin_amdgcn_s_setprio(1);
#pragma unroll
    for (int ks = 0; ks < 4; ++ks)
      o0 = mfma32(lds_frag(&Vc[voff[0][ks]]), pa[ks], o0);
#pragma unroll
    for (int ks = 0; ks < 4; ++ks)
      o1 = mfma32(lds_frag(&Vc[voff[1][ks]]), pa[ks], o1);
    __builtin_amdgcn_s_setprio(0);

    __syncthreads();
  }

  const float inv = 1.0f / ln;
  u16* orow = Ob + ((size_t)(b2 * 2048 + q0 + q)) * 1024 + h * 64;
#pragma unroll
  for (int g = 0; g < 4; ++g) {
    u16x4 pk;
    pk.x = f2bf(o0[4 * g + 0] * inv);
    pk.y = f2bf(o0[4 * g + 1] * inv);
    pk.z = f2bf(o0[4 * g + 2] * inv);
    pk.w = f2bf(o0[4 * g + 3] * inv);
    *(u16x4*)&orow[8 * g + 4 * hi] = pk;
  }
#pragma unroll
  for (int g = 0; g < 4; ++g) {
    u16x4 pk;
    pk.x = f2bf(o1[4 * g + 0] * inv);
    pk.y = f2bf(o1[4 * g + 1] * inv);
    pk.z = f2bf(o1[4 * g + 2] * inv);
    pk.w = f2bf(o1[4 * g + 3] * inv);
    *(u16x4*)&orow[32 + 8 * g + 4 * hi] = pk;
  }
}

// ---------- launcher ----------
extern "C" void kernel_launch(void* const* d_in, const int* in_sizes, int n_in,
                              void* d_out, int out_size, void* d_ws,
                              size_t ws_size, hipStream_t stream) {
  const float* q  = (const float*)d_in[0];
  const float* k  = (const float*)d_in[1];
  const float* v  = (const float*)d_in[2];
  const float* Wq = (const float*)d_in[3];
  const float* bq = (const float*)d_in[4];
  const float* Wk = (const float*)d_in[5];
  const float* bk = (const float*)d_in[6];
  const float* Wv = (const float*)d_in[7];
  const float* bv = (const float*)d_in[8];
  const float* Wo = (const float*)d_in[9];
  const float* bo = (const float*)d_in[10];
  float* out = (float*)d_out;

  u16* ws = (u16*)d_ws;
  u16* Wqb = ws;              // [1024,1024] bf16 x4
  u16* Wkb = Wqb + NW;
  u16* Wvb = Wkb + NW;
  u16* Wob = Wvb + NW;
  u16* Qn  = Wob + NW;        // [B,S,1024] natural
  u16* Kn  = Qn + NBIG;       // [B,S,1024] natural
  u16* Vt  = Kn + NBIG;       // [B,H,64,S] transposed
  u16* O   = Vt + NBIG;       // [B,S,H*64] attn output (bf16)

  cvt_kernel<<<dim3(1024, 4, 1), 256, 0, stream>>>(Wq, Wk, Wv, Wo, Wqb, Wkb,
                                                   Wvb, Wob);
  proj_kernel<<<dim3(64, 8, 3), 256, 0, stream>>>(q, k, v, Wqb, Wkb, Wvb, bq,
                                                  bk, bv, Qn, Kn, Vt);
  attn_kernel<<<dim3(8, 64, 1), 512, 0, stream>>>(Qn, Kn, Vt, O);
  outproj_kernel<<<dim3(64, 8, 1), 256, 0, stream>>>(O, Wob, bo, out);
}

// Round 19
// 223.283 us; speedup vs baseline: 1.2056x; 1.2056x over previous
//
#include <hip/hip_runtime.h>
#include <stdint.h>

#define DEVI static __device__ __forceinline__

typedef __attribute__((ext_vector_type(4))) float f32x4;
typedef __attribute__((ext_vector_type(16))) float f32x16;
typedef __attribute__((ext_vector_type(8))) __bf16 bf16x8;
typedef __attribute__((ext_vector_type(4))) uint16_t u16x4;
typedef uint16_t u16;

// ---------- helpers ----------
DEVI u16 f2bf(float f) {  // round-to-nearest-even fp32 -> bf16
  union { float f; uint32_t u; } v; v.f = f;
  uint32_t r = v.u + 0x7FFFu + ((v.u >> 16) & 1u);
  return (u16)(r >> 16);
}

DEVI f32x4 mfma16(bf16x8 a, bf16x8 b, f32x4 c) {
  return __builtin_amdgcn_mfma_f32_16x16x32_bf16(a, b, c, 0, 0, 0);
}

DEVI f32x16 mfma32(bf16x8 a, bf16x8 b, f32x16 c) {
  return __builtin_amdgcn_mfma_f32_32x32x16_bf16(a, b, c, 0, 0, 0);
}

DEVI void load_lds16(const void* g, void* l) {  // async global->LDS, 16B/lane
  __builtin_amdgcn_global_load_lds(
      (const __attribute__((address_space(1))) void*)g,
      (__attribute__((address_space(3))) void*)l, 16, 0, 0);
}

DEVI bf16x8 lds_frag(const u16* p) { return *(const bf16x8*)p; }

DEVI f32x16 zero16() {
  f32x16 z;
#pragma unroll
  for (int i = 0; i < 16; ++i) z[i] = 0.f;
  return z;
}

// hardware exp2 (1 instruction)
DEVI float exp2_hw(float x) {
  float r;
  asm("v_exp_f32 %0, %1" : "=v"(r) : "v"(x));
  return r;
}

// pack 2 f32 -> bf16x2 word in ONE instruction (RNE)
DEVI uint32_t cvtpk(float lo, float hi) {
  uint32_t r;
  asm("v_cvt_pk_bf16_f32 %0, %1, %2" : "=v"(r) : "v"(lo), "v"(hi));
  return r;
}

// 8 fp32 (two f32x4) -> bf16x8 via 4 cvt_pk
DEVI bf16x8 cvt8v(f32x4 lo, f32x4 hi) {
  union { uint32_t u[4]; bf16x8 v; } c;
  c.u[0] = cvtpk(lo[0], lo[1]);
  c.u[1] = cvtpk(lo[2], lo[3]);
  c.u[2] = cvtpk(hi[0], hi[1]);
  c.u[3] = cvtpk(hi[2], hi[3]);
  return c.v;
}

// 3-input max in one instruction (T17)
DEVI float max3f(float a, float b, float c) {
  float r;
  asm("v_max3_f32 %0, %1, %2, %3" : "=v"(r) : "v"(a), "v"(b), "v"(c));
  return r;
}

// cross-half exchange via shfl (for scalar reduces; coalescing-proof)
DEVI float partner_f(float x) { return __shfl_xor(x, 32, 64); }

// REAL v_permlane32_swap_b32: exchanges a.hi-lanes <-> b.lo-lanes.
// ONLY safe when a and b hold DISTINCT values (same-value operands may be
// register-coalesced -> swap-with-self; that was the round-3 bug).
DEVI void pswap_asm(uint32_t& a, uint32_t& b) {
  asm("v_permlane32_swap_b32 %0, %1" : "+v"(a), "+v"(b));
}

// ---------- fp32 -> bf16 conversion (WEIGHTS ONLY) ----------
#define NBIG (4 * 2048 * 1024)
#define NW (1024 * 1024)

__global__ __launch_bounds__(256) void cvt_kernel(const float* Wq,
                                                  const float* Wk,
                                                  const float* Wv,
                                                  const float* Wo, u16* Wqb,
                                                  u16* Wkb, u16* Wvb,
                                                  u16* Wob) {
  const float* src;
  u16* dst;
  switch (blockIdx.y) {
    case 0: src = Wq; dst = Wqb; break;
    case 1: src = Wk; dst = Wkb; break;
    case 2: src = Wv; dst = Wvb; break;
    default: src = Wo; dst = Wob; break;
  }
  int i = (blockIdx.x * 256 + threadIdx.x) * 4;
  if (i >= NW) return;
  float4 f = *(const float4*)&src[i];
  u16x4 o;
  o.x = f2bf(f.x); o.y = f2bf(f.y); o.z = f2bf(f.z); o.w = f2bf(f.w);
  *(u16x4*)&dst[i] = o;
}

// ---------- QKV projection: fp32 A staged via global_load_lds, cvt on read.
// BK=32, double-buffered, 48 KB LDS (2 blocks/CU) -- best measured (r17).
__global__ __launch_bounds__(256) void proj_kernel(
    const float* qx, const float* kx, const float* vx, const u16* Wq,
    const u16* Wk, const u16* Wv, const float* bq, const float* bk,
    const float* bv, u16* Qn, u16* Kn, u16* Vt) {
  __shared__ __align__(16) float Af[2][128 * 32];  // 32 KB
  __shared__ __align__(16) u16 Bs[2][128 * 32];    // 16 KB

  const int z = blockIdx.z;
  const float* A32 = z == 0 ? qx : z == 1 ? kx : vx;
  const u16* W = z == 0 ? Wq : z == 1 ? Wk : Wv;
  const float* bias = z == 0 ? bq : z == 1 ? bk : bv;
  const int bm = blockIdx.x, bn = blockIdx.y;

  const int tid = threadIdx.x;
  const int w = tid >> 6, l = tid & 63;
  const int lr = l & 15, lg = l >> 4;
  const int wr = (w >> 1) * 64, wc = (w & 1) * 64;

  // ---- A staging: chunk c covers rows 8c..8c+7; lane l -> row 8c+(l>>3),
  //      swizzled 16B granule (l&7)^((l>>3)&7); dst linear c*1KB + l*16B ----
  const int ar = l >> 3;
  const int aj = (l & 7) ^ ar;
  const float* gA[4];
  int laoff[4];
#pragma unroll
  for (int i = 0; i < 4; ++i) {
    const int c = 4 * w + i;
    gA[i] = A32 + (size_t)(bm * 128 + c * 8 + ar) * 1024 + aj * 4;
    laoff[i] = c * 256;  // fp32 units
  }
  // ---- B staging ----
  const int c0 = 2 * w, c1 = 2 * w + 1;
  const u16* gB0 = W + (size_t)(bn * 128 + c0 * 16 + (l >> 2)) * 1024 + (l & 3) * 8;
  const u16* gB1 = W + (size_t)(bn * 128 + c1 * 16 + (l >> 2)) * 1024 + (l & 3) * 8;
  const int sb0 = c0 * 512, sb1 = c1 * 512;  // u16 units

  // ---- read offsets ----
  int aoff0[4], aoff1[4], boff[4];
#pragma unroll
  for (int mi = 0; mi < 4; ++mi) {
    const int row = wr + mi * 16 + lr;
    aoff0[mi] = row * 32 + (((lg * 2)     ) ^ (row & 7)) * 4;  // fp32 units
    aoff1[mi] = row * 32 + (((lg * 2) + 1) ^ (row & 7)) * 4;
  }
#pragma unroll
  for (int nj = 0; nj < 4; ++nj) boff[nj] = (wc + nj * 16 + lr) * 32 + lg * 8;

  f32x4 acc[4][4];
#pragma unroll
  for (int i = 0; i < 4; ++i)
#pragma unroll
    for (int j = 0; j < 4; ++j) acc[i][j] = (f32x4){0.f, 0.f, 0.f, 0.f};

  // prologue: stage tile 0 -> buf 0 (6 loads/wave)
#pragma unroll
  for (int i = 0; i < 4; ++i) load_lds16(gA[i], &Af[0][laoff[i]]);
  load_lds16(gB0, &Bs[0][sb0]);
  load_lds16(gB1, &Bs[0][sb1]);
  __syncthreads();

  int cur = 0;
  for (int k0 = 0; k0 < 1024; k0 += 32) {
    const int nxt = cur ^ 1;
    if (k0 + 32 < 1024) {
#pragma unroll
      for (int i = 0; i < 4; ++i)
        load_lds16(gA[i] + k0 + 32, &Af[nxt][laoff[i]]);
      load_lds16(gB0 + k0 + 32, &Bs[nxt][sb0]);
      load_lds16(gB1 + k0 + 32, &Bs[nxt][sb1]);
    }
    const float* Ac = Af[cur];
    const u16* Bc = Bs[cur];
    bf16x8 af[4], bff[4];
#pragma unroll
    for (int mi = 0; mi < 4; ++mi) {
      const f32x4 lo = *(const f32x4*)&Ac[aoff0[mi]];
      const f32x4 hi = *(const f32x4*)&Ac[aoff1[mi]];
      af[mi] = cvt8v(lo, hi);
    }
#pragma unroll
    for (int nj = 0; nj < 4; ++nj) bff[nj] = lds_frag(&Bc[boff[nj]]);
#pragma unroll
    for (int mi = 0; mi < 4; ++mi)
#pragma unroll
      for (int nj = 0; nj < 4; ++nj)
        acc[mi][nj] = mfma16(af[mi], bff[nj], acc[mi][nj]);
    __syncthreads();
    cur = nxt;
  }

  // ---- epilogue: Q/K natural coalesced; V transposed scatter ----
#pragma unroll
  for (int nj = 0; nj < 4; ++nj) {
    const int col = bn * 128 + wc + nj * 16 + lr;
    const float bb = bias[col];
#pragma unroll
    for (int mi = 0; mi < 4; ++mi) {
      const int m0 = bm * 128 + wr + mi * 16 + lg * 4;
      if (z < 2) {
        u16* dst = (z == 0) ? Qn : Kn;
#pragma unroll
        for (int r = 0; r < 4; ++r)
          dst[(size_t)(m0 + r) * 1024 + col] = f2bf(acc[mi][nj][r] + bb);
      } else {
        const int b = m0 >> 11;         // batch
        const int s0 = m0 & 2047;       // seq position
        const int h = col >> 6, d = col & 63;
        u16x4 pk;
        pk.x = f2bf(acc[mi][nj][0] + bb);
        pk.y = f2bf(acc[mi][nj][1] + bb);
        pk.z = f2bf(acc[mi][nj][2] + bb);
        pk.w = f2bf(acc[mi][nj][3] + bb);
        *(u16x4*)&Vt[(((size_t)(b * 16 + h) * 64) + d) * 2048 + s0] = pk;
      }
    }
  }
}

// ---------- GEMM core: single-barrier double-buffered (r10, proven) ---------
DEVI void gemm_core_1024_db(const u16* __restrict__ A,
                            const u16* __restrict__ Bm, int bm, int bn,
                            u16* As, u16* Bs, f32x4 acc[4][4]) {
  const int tid = threadIdx.x;
  const int w = tid >> 6, l = tid & 63;
  const int lr = l & 15, lg = l >> 4;
  const int wr = (w >> 1) * 64, wc = (w & 1) * 64;

  for (int i = 0; i < 4; ++i)
    for (int j = 0; j < 4; ++j) acc[i][j] = (f32x4){0.f, 0.f, 0.f, 0.f};

  const int c0 = 2 * w, c1 = 2 * w + 1;
  const u16* gA0 = A + (size_t)(bm * 128 + c0 * 16 + (l >> 2)) * 1024 + (l & 3) * 8;
  const u16* gA1 = A + (size_t)(bm * 128 + c1 * 16 + (l >> 2)) * 1024 + (l & 3) * 8;
  const u16* gB0 = Bm + (size_t)(bn * 128 + c0 * 16 + (l >> 2)) * 1024 + (l & 3) * 8;
  const u16* gB1 = Bm + (size_t)(bn * 128 + c1 * 16 + (l >> 2)) * 1024 + (l & 3) * 8;
  const int sA0 = c0 * 512, sA1 = c1 * 512;

  int aoff[4], boff[4];
#pragma unroll
  for (int mi = 0; mi < 4; ++mi) aoff[mi] = (wr + mi * 16 + lr) * 32 + lg * 8;
#pragma unroll
  for (int nj = 0; nj < 4; ++nj) boff[nj] = (wc + nj * 16 + lr) * 32 + lg * 8;

  load_lds16(gA0, As + sA0);
  load_lds16(gA1, As + sA1);
  load_lds16(gB0, Bs + sA0);
  load_lds16(gB1, Bs + sA1);
  __syncthreads();

  int cur = 0;
  for (int k0 = 0; k0 < 1024; k0 += 32) {
    const int nxt = cur ^ 1;
    if (k0 + 32 < 1024) {
      load_lds16(gA0 + k0 + 32, As + nxt * 4096 + sA0);
      load_lds16(gA1 + k0 + 32, As + nxt * 4096 + sA1);
      load_lds16(gB0 + k0 + 32, Bs + nxt * 4096 + sA0);
      load_lds16(gB1 + k0 + 32, Bs + nxt * 4096 + sA1);
    }
    const u16* Ac = As + cur * 4096;
    const u16* Bc = Bs + cur * 4096;
    bf16x8 af[4], bff[4];
#pragma unroll
    for (int mi = 0; mi < 4; ++mi) af[mi] = lds_frag(&Ac[aoff[mi]]);
#pragma unroll
    for (int nj = 0; nj < 4; ++nj) bff[nj] = lds_frag(&Bc[boff[nj]]);
#pragma unroll
    for (int mi = 0; mi < 4; ++mi)
#pragma unroll
      for (int nj = 0; nj < 4; ++nj)
        acc[mi][nj] = mfma16(af[mi], bff[nj], acc[mi][nj]);
    __syncthreads();
    cur = nxt;
  }
}

// ---------- output projection ----------
__global__ __launch_bounds__(256) void outproj_kernel(const u16* O,
                                                      const u16* Wo,
                                                      const float* bo,
                                                      float* out) {
  __shared__ __align__(16) u16 As[2 * 128 * 32];
  __shared__ __align__(16) u16 Bs[2 * 128 * 32];
  f32x4 acc[4][4];
  gemm_core_1024_db(O, Wo, blockIdx.x, blockIdx.y, As, Bs, acc);

  const int tid = threadIdx.x;
  const int w = tid >> 6, l = tid & 63;
  const int lr = l & 15, lg = l >> 4;
  const int wr = (w >> 1) * 64, wc = (w & 1) * 64;
#pragma unroll
  for (int nj = 0; nj < 4; ++nj) {
    const int col = blockIdx.y * 128 + wc + nj * 16 + lr;
    const float bb = bo[col];
#pragma unroll
    for (int mi = 0; mi < 4; ++mi) {
      const int m0 = blockIdx.x * 128 + wr + mi * 16 + lg * 4;
#pragma unroll
      for (int r = 0; r < 4; ++r)
        out[(size_t)(m0 + r) * 1024 + col] = acc[mi][nj][r] + bb;
    }
  }
}

// ---------- flash attention v7n: natural-layout Q/K ([B,S,H*64]) ------------
#define LDPK 72
#define NT 32  // 2048 / 64
__global__ __launch_bounds__(512) void attn_kernel(const u16* Qn, const u16* Kn,
                                                   const u16* Vt, u16* Ob) {
  __shared__ __align__(16) u16 Kl[2][64 * LDPK];
  __shared__ __align__(16) u16 Vl[2][64 * LDPK];

  const int tid = threadIdx.x, w = tid >> 6, l = tid & 63;
  const int q = l & 31, hi = l >> 5;
  const int bh = blockIdx.y;
  const int b2 = bh >> 4, h = bh & 15;
  const int q0 = blockIdx.x * 256 + w * 32;
  const u16* Qh = Qn + (size_t)b2 * 2048 * 1024 + h * 64;
  const u16* Kh = Kn + (size_t)b2 * 2048 * 1024 + h * 64;
  const u16* Vh = Vt + (size_t)bh * 64 * 2048;

  const float SC2 = 0.1803368801f;  // 0.125 * log2(e)

  bf16x8 qf[4];
#pragma unroll
  for (int ds = 0; ds < 4; ++ds)
    qf[ds] = *(const bf16x8*)&Qh[(size_t)(q0 + q) * 1024 + ds * 16 + hi * 8];

  f32x16 o0 = zero16(), o1 = zero16();
  float m = -1.0e30f, ln = 0.f;

  const int srow = tid >> 3, g0 = tid & 7;

  int koff[2][4], voff[2][4];
#pragma unroll
  for (int kb = 0; kb < 2; ++kb)
#pragma unroll
    for (int ds = 0; ds < 4; ++ds)
      koff[kb][ds] = (kb * 32 + q) * LDPK + ds * 16 + hi * 8;
#pragma unroll
  for (int db = 0; db < 2; ++db)
#pragma unroll
    for (int ks = 0; ks < 4; ++ks)
      voff[db][ks] = (db * 32 + q) * LDPK + ks * 16 + hi * 8;

  bf16x8 kv = *(const bf16x8*)&Kh[(size_t)srow * 1024 + g0 * 8];
  bf16x8 vv = *(const bf16x8*)&Vh[(size_t)srow * 2048 + g0 * 8];
  *(bf16x8*)&Kl[0][srow * LDPK + g0 * 8] = kv;
  *(bf16x8*)&Vl[0][srow * LDPK + g0 * 8] = vv;
  kv = *(const bf16x8*)&Kh[(size_t)(64 + srow) * 1024 + g0 * 8];
  vv = *(const bf16x8*)&Vh[(size_t)srow * 2048 + 64 + g0 * 8];
  const u16* gk = Kh + (size_t)(2 * 64 + srow) * 1024 + g0 * 8;
  const u16* gv = Vh + (size_t)srow * 2048 + 2 * 64 + g0 * 8;
  __syncthreads();

  for (int kt = 0; kt < NT; ++kt) {
    const int cur = kt & 1;
    const u16* Kc = Kl[cur];
    const u16* Vc = Vl[cur];

    f32x16 c0 = zero16(), c1 = zero16();
    __builtin_amdgcn_s_setprio(1);
#pragma unroll
    for (int ds = 0; ds < 4; ++ds)
      c0 = mfma32(lds_frag(&Kc[koff[0][ds]]), qf[ds], c0);
#pragma unroll
    for (int ds = 0; ds < 4; ++ds)
      c1 = mfma32(lds_frag(&Kc[koff[1][ds]]), qf[ds], c1);
    __builtin_amdgcn_s_setprio(0);

    float tm[16];
#pragma unroll
    for (int r = 0; r < 16; ++r) tm[r] = fmaxf(c0[r], c1[r]);
    {
      const float m0_ = max3f(tm[0], tm[1], tm[2]);
      const float m1_ = max3f(tm[3], tm[4], tm[5]);
      const float m2_ = max3f(tm[6], tm[7], tm[8]);
      const float m3_ = max3f(tm[9], tm[10], tm[11]);
      const float m4_ = max3f(tm[12], tm[13], tm[14]);
      const float a_ = max3f(m0_, m1_, m2_);
      const float b_ = max3f(m3_, m4_, tm[15]);
      tm[0] = fmaxf(a_, b_);
    }
    const float mx = fmaxf(tm[0], partner_f(tm[0]));
    if (!__all(mx - m <= 64.0f)) {
      const float mnew = fmaxf(m, mx);
      const float a = exp2_hw((m - mnew) * SC2);
      m = mnew;
#pragma unroll
      for (int r = 0; r < 16; ++r) { o0[r] *= a; o1[r] *= a; }
      ln *= a;
    }
    const float m2 = m * SC2;
    float p0[16], p1[16];
#pragma unroll
    for (int r = 0; r < 16; ++r) {
      p0[r] = exp2_hw(__builtin_fmaf(c0[r], SC2, -m2));
      p1[r] = exp2_hw(__builtin_fmaf(c1[r], SC2, -m2));
    }
    float ts[16];
#pragma unroll
    for (int r = 0; r < 16; ++r) ts[r] = p0[r] + p1[r];
#pragma unroll
    for (int s = 8; s > 0; s >>= 1)
#pragma unroll
      for (int r = 0; r < s; ++r) ts[r] += ts[r + s];
    ln += ts[0] + partner_f(ts[0]);

    if (kt + 1 < NT) {
      *(bf16x8*)&Kl[cur ^ 1][srow * LDPK + g0 * 8] = kv;
      *(bf16x8*)&Vl[cur ^ 1][srow * LDPK + g0 * 8] = vv;
    }
    if (kt + 2 < NT) {
      kv = *(const bf16x8*)gk;
      vv = *(const bf16x8*)gv;
      gk += 64 * 1024; gv += 64;
    }

    uint32_t wv[16];
#pragma unroll
    for (int i = 0; i < 8; ++i) {
      wv[i]     = cvtpk(p0[2 * i], p0[2 * i + 1]);
      wv[8 + i] = cvtpk(p1[2 * i], p1[2 * i + 1]);
    }
    bf16x8 pa[4];
#pragma unroll
    for (int ks = 0; ks < 4; ++ks) {
      const int base = (ks >> 1) * 8 + 4 * (ks & 1);
      uint32_t x0 = wv[base],     y0 = wv[base + 2];
      uint32_t x1 = wv[base + 1], y1 = wv[base + 3];
      pswap_asm(x0, y0);
      pswap_asm(x1, y1);
      union { uint32_t u[4]; bf16x8 v; } cvt;
      cvt.u[0] = x0; cvt.u[1] = x1; cvt.u[2] = y0; cvt.u[3] = y1;
      pa[ks] = cvt.v;
    }

    __builtin_amdgcn_s_setprio(1);
#pragma unroll
    for (int ks = 0; ks < 4; ++ks)
      o0 = mfma32(lds_frag(&Vc[voff[0][ks]]), pa[ks], o0);
#pragma unroll
    for (int ks = 0; ks < 4; ++ks)
      o1 = mfma32(lds_frag(&Vc[voff[1][ks]]), pa[ks], o1);
    __builtin_amdgcn_s_setprio(0);

    __syncthreads();
  }

  const float inv = 1.0f / ln;
  u16* orow = Ob + ((size_t)(b2 * 2048 + q0 + q)) * 1024 + h * 64;
#pragma unroll
  for (int g = 0; g < 4; ++g) {
    u16x4 pk;
    pk.x = f2bf(o0[4 * g + 0] * inv);
    pk.y = f2bf(o0[4 * g + 1] * inv);
    pk.z = f2bf(o0[4 * g + 2] * inv);
    pk.w = f2bf(o0[4 * g + 3] * inv);
    *(u16x4*)&orow[8 * g + 4 * hi] = pk;
  }
#pragma unroll
  for (int g = 0; g < 4; ++g) {
    u16x4 pk;
    pk.x = f2bf(o1[4 * g + 0] * inv);
    pk.y = f2bf(o1[4 * g + 1] * inv);
    pk.z = f2bf(o1[4 * g + 2] * inv);
    pk.w = f2bf(o1[4 * g + 3] * inv);
    *(u16x4*)&orow[32 + 8 * g + 4 * hi] = pk;
  }
}

// ---------- launcher ----------
extern "C" void kernel_launch(void* const* d_in, const int* in_sizes, int n_in,
                              void* d_out, int out_size, void* d_ws,
                              size_t ws_size, hipStream_t stream) {
  const float* q  = (const float*)d_in[0];
  const float* k  = (const float*)d_in[1];
  const float* v  = (const float*)d_in[2];
  const float* Wq = (const float*)d_in[3];
  const float* bq = (const float*)d_in[4];
  const float* Wk = (const float*)d_in[5];
  const float* bk = (const float*)d_in[6];
  const float* Wv = (const float*)d_in[7];
  const float* bv = (const float*)d_in[8];
  const float* Wo = (const float*)d_in[9];
  const float* bo = (const float*)d_in[10];
  float* out = (float*)d_out;

  u16* ws = (u16*)d_ws;
  u16* Wqb = ws;              // [1024,1024] bf16 x4
  u16* Wkb = Wqb + NW;
  u16* Wvb = Wkb + NW;
  u16* Wob = Wvb + NW;
  u16* Qn  = Wob + NW;        // [B,S,1024] natural
  u16* Kn  = Qn + NBIG;       // [B,S,1024] natural
  u16* Vt  = Kn + NBIG;       // [B,H,64,S] transposed
  u16* O   = Vt + NBIG;       // [B,S,H*64] attn output (bf16)

  cvt_kernel<<<dim3(1024, 4, 1), 256, 0, stream>>>(Wq, Wk, Wv, Wo, Wqb, Wkb,
                                                   Wvb, Wob);
  proj_kernel<<<dim3(64, 8, 3), 256, 0, stream>>>(q, k, v, Wqb, Wkb, Wvb, bq,
                                                  bk, bv, Qn, Kn, Vt);
  attn_kernel<<<dim3(8, 64, 1), 512, 0, stream>>>(Qn, Kn, Vt, O);
  outproj_kernel<<<dim3(64, 8, 1), 256, 0, stream>>>(O, Wob, bo, out);
}

// Round 20
// 213.013 us; speedup vs baseline: 1.2638x; 1.0482x over previous
//
#include <hip/hip_runtime.h>
#include <stdint.h>

#define DEVI static __device__ __forceinline__

typedef __attribute__((ext_vector_type(4))) float f32x4;
typedef __attribute__((ext_vector_type(16))) float f32x16;
typedef __attribute__((ext_vector_type(8))) __bf16 bf16x8;
typedef __attribute__((ext_vector_type(4))) uint16_t u16x4;
typedef uint16_t u16;

// ---------- helpers ----------
DEVI u16 f2bf(float f) {  // round-to-nearest-even fp32 -> bf16
  union { float f; uint32_t u; } v; v.f = f;
  uint32_t r = v.u + 0x7FFFu + ((v.u >> 16) & 1u);
  return (u16)(r >> 16);
}

DEVI f32x4 mfma16(bf16x8 a, bf16x8 b, f32x4 c) {
  return __builtin_amdgcn_mfma_f32_16x16x32_bf16(a, b, c, 0, 0, 0);
}

DEVI f32x16 mfma32(bf16x8 a, bf16x8 b, f32x16 c) {
  return __builtin_amdgcn_mfma_f32_32x32x16_bf16(a, b, c, 0, 0, 0);
}

DEVI void load_lds16(const void* g, void* l) {  // async global->LDS, 16B/lane
  __builtin_amdgcn_global_load_lds(
      (const __attribute__((address_space(1))) void*)g,
      (__attribute__((address_space(3))) void*)l, 16, 0, 0);
}

DEVI bf16x8 lds_frag(const u16* p) { return *(const bf16x8*)p; }

DEVI f32x16 zero16() {
  f32x16 z;
#pragma unroll
  for (int i = 0; i < 16; ++i) z[i] = 0.f;
  return z;
}

// hardware exp2 (1 instruction)
DEVI float exp2_hw(float x) {
  float r;
  asm("v_exp_f32 %0, %1" : "=v"(r) : "v"(x));
  return r;
}

// pack 2 f32 -> bf16x2 word in ONE instruction (RNE)
DEVI uint32_t cvtpk(float lo, float hi) {
  uint32_t r;
  asm("v_cvt_pk_bf16_f32 %0, %1, %2" : "=v"(r) : "v"(lo), "v"(hi));
  return r;
}

// 8 fp32 (two f32x4) -> bf16x8 via 4 cvt_pk
DEVI bf16x8 cvt8v(f32x4 lo, f32x4 hi) {
  union { uint32_t u[4]; bf16x8 v; } c;
  c.u[0] = cvtpk(lo[0], lo[1]);
  c.u[1] = cvtpk(lo[2], lo[3]);
  c.u[2] = cvtpk(hi[0], hi[1]);
  c.u[3] = cvtpk(hi[2], hi[3]);
  return c.v;
}

// 3-input max in one instruction (T17)
DEVI float max3f(float a, float b, float c) {
  float r;
  asm("v_max3_f32 %0, %1, %2, %3" : "=v"(r) : "v"(a), "v"(b), "v"(c));
  return r;
}

// cross-half exchange via shfl (for scalar reduces; coalescing-proof)
DEVI float partner_f(float x) { return __shfl_xor(x, 32, 64); }

// REAL v_permlane32_swap_b32: exchanges a.hi-lanes <-> b.lo-lanes.
// ONLY safe when a and b hold DISTINCT values (same-value operands may be
// register-coalesced -> swap-with-self; that was the round-3 bug).
DEVI void pswap_asm(uint32_t& a, uint32_t& b) {
  asm("v_permlane32_swap_b32 %0, %1" : "+v"(a), "+v"(b));
}

// ---------- fp32 -> bf16 conversion (WEIGHTS ONLY) ----------
#define NBIG (4 * 2048 * 1024)
#define NW (1024 * 1024)

__global__ __launch_bounds__(256) void cvt_kernel(const float* Wq,
                                                  const float* Wk,
                                                  const float* Wv,
                                                  const float* Wo, u16* Wqb,
                                                  u16* Wkb, u16* Wvb,
                                                  u16* Wob) {
  const float* src;
  u16* dst;
  switch (blockIdx.y) {
    case 0: src = Wq; dst = Wqb; break;
    case 1: src = Wk; dst = Wkb; break;
    case 2: src = Wv; dst = Wvb; break;
    default: src = Wo; dst = Wob; break;
  }
  int i = (blockIdx.x * 256 + threadIdx.x) * 4;
  if (i >= NW) return;
  float4 f = *(const float4*)&src[i];
  u16x4 o;
  o.x = f2bf(f.x); o.y = f2bf(f.y); o.z = f2bf(f.z); o.w = f2bf(f.w);
  *(u16x4*)&dst[i] = o;
}

// ---------- QKV projection: 128x256 tile, 8 waves (2x4), BK=32 --------------
// Halves drain-bound block-steps (768 blocks, 3 grid-rounds) while KEEPING
// 2 blocks/CU (64 KB LDS) and per-wave step work identical to the r17 core
// (16 MFMAs, 4 staging loads). fp32 A staged via global_load_lds with the
// proven r17 swizzle; B linear (proj is drain-bound, not LDS-bound: r12 T2
// null). Q/K natural epilogue; V transposed scatter.
__global__ __launch_bounds__(512) void proj_kernel(
    const float* qx, const float* kx, const float* vx, const u16* Wq,
    const u16* Wk, const u16* Wv, const float* bq, const float* bk,
    const float* bv, u16* Qn, u16* Kn, u16* Vt) {
  __shared__ __align__(16) float Af[2][128 * 32];  // 32 KB
  __shared__ __align__(16) u16 Bs[2][256 * 32];    // 32 KB

  const int z = blockIdx.z;
  const float* A32 = z == 0 ? qx : z == 1 ? kx : vx;
  const u16* W = z == 0 ? Wq : z == 1 ? Wk : Wv;
  const float* bias = z == 0 ? bq : z == 1 ? bk : bv;
  const int bm = blockIdx.x, bn = blockIdx.y;

  const int tid = threadIdx.x;
  const int w = tid >> 6, l = tid & 63;
  const int lr = l & 15, lg = l >> 4;
  const int wm = w >> 2, wn = w & 3;       // 2 M-waves x 4 N-waves
  const int wr = wm * 64, wc = wn * 64;

  // ---- A staging: 16 chunks of 1KB (8 rows x 32 fp32); wave w: 2w, 2w+1.
  //      lane l -> row 8c+(l>>3), swizzled 16B granule (l&7)^(row&7). ----
  const int ar = l >> 3;
  const int aj = (l & 7) ^ ar;             // (row&7) == ar for 8-row chunks
  const float* gA[2];
  int laoff[2];
#pragma unroll
  for (int i = 0; i < 2; ++i) {
    const int c = 2 * w + i;
    gA[i] = A32 + (size_t)(bm * 128 + c * 8 + ar) * 1024 + aj * 4;
    laoff[i] = c * 256;  // fp32 units
  }
  // ---- B staging: 16 chunks of 1KB (16 rows x 32 bf16); wave w: 2w, 2w+1.
  //      lane l -> row 16c+(l>>2), granule l&3 (linear). ----
  const u16* gB[2];
  int lboff[2];
#pragma unroll
  for (int i = 0; i < 2; ++i) {
    const int c = 2 * w + i;
    gB[i] = W + (size_t)(bn * 256 + c * 16 + (l >> 2)) * 1024 + (l & 3) * 8;
    lboff[i] = c * 512;  // u16 units
  }

  // ---- read offsets ----
  int aoff0[4], aoff1[4], boff[4];
#pragma unroll
  for (int mi = 0; mi < 4; ++mi) {
    const int row = wr + mi * 16 + lr;
    aoff0[mi] = row * 32 + (((lg * 2)     ) ^ (row & 7)) * 4;  // fp32 units
    aoff1[mi] = row * 32 + (((lg * 2) + 1) ^ (row & 7)) * 4;
  }
#pragma unroll
  for (int nj = 0; nj < 4; ++nj) boff[nj] = (wc + nj * 16 + lr) * 32 + lg * 8;

  f32x4 acc[4][4];
#pragma unroll
  for (int i = 0; i < 4; ++i)
#pragma unroll
    for (int j = 0; j < 4; ++j) acc[i][j] = (f32x4){0.f, 0.f, 0.f, 0.f};

  // prologue: stage tile 0 -> buf 0 (4 loads/wave)
#pragma unroll
  for (int i = 0; i < 2; ++i) load_lds16(gA[i], &Af[0][laoff[i]]);
#pragma unroll
  for (int i = 0; i < 2; ++i) load_lds16(gB[i], &Bs[0][lboff[i]]);
  __syncthreads();

  int cur = 0;
  for (int k0 = 0; k0 < 1024; k0 += 32) {
    const int nxt = cur ^ 1;
    if (k0 + 32 < 1024) {
#pragma unroll
      for (int i = 0; i < 2; ++i)
        load_lds16(gA[i] + k0 + 32, &Af[nxt][laoff[i]]);
#pragma unroll
      for (int i = 0; i < 2; ++i)
        load_lds16(gB[i] + k0 + 32, &Bs[nxt][lboff[i]]);
    }
    const float* Ac = Af[cur];
    const u16* Bc = Bs[cur];
    bf16x8 af[4], bff[4];
#pragma unroll
    for (int mi = 0; mi < 4; ++mi) {
      const f32x4 lo = *(const f32x4*)&Ac[aoff0[mi]];
      const f32x4 hi = *(const f32x4*)&Ac[aoff1[mi]];
      af[mi] = cvt8v(lo, hi);
    }
#pragma unroll
    for (int nj = 0; nj < 4; ++nj) bff[nj] = lds_frag(&Bc[boff[nj]]);
#pragma unroll
    for (int mi = 0; mi < 4; ++mi)
#pragma unroll
      for (int nj = 0; nj < 4; ++nj)
        acc[mi][nj] = mfma16(af[mi], bff[nj], acc[mi][nj]);
    __syncthreads();
    cur = nxt;
  }

  // ---- epilogue: Q/K natural coalesced; V transposed scatter ----
#pragma unroll
  for (int nj = 0; nj < 4; ++nj) {
    const int col = bn * 256 + wc + nj * 16 + lr;
    const float bb = bias[col];
#pragma unroll
    for (int mi = 0; mi < 4; ++mi) {
      const int m0 = bm * 128 + wr + mi * 16 + lg * 4;
      if (z < 2) {
        u16* dst = (z == 0) ? Qn : Kn;
#pragma unroll
        for (int r = 0; r < 4; ++r)
          dst[(size_t)(m0 + r) * 1024 + col] = f2bf(acc[mi][nj][r] + bb);
      } else {
        const int b = m0 >> 11;         // batch
        const int s0 = m0 & 2047;       // seq position
        const int h = col >> 6, d = col & 63;
        u16x4 pk;
        pk.x = f2bf(acc[mi][nj][0] + bb);
        pk.y = f2bf(acc[mi][nj][1] + bb);
        pk.z = f2bf(acc[mi][nj][2] + bb);
        pk.w = f2bf(acc[mi][nj][3] + bb);
        *(u16x4*)&Vt[(((size_t)(b * 16 + h) * 64) + d) * 2048 + s0] = pk;
      }
    }
  }
}

// ---------- GEMM core: single-barrier double-buffered (r10, proven) ---------
DEVI void gemm_core_1024_db(const u16* __restrict__ A,
                            const u16* __restrict__ Bm, int bm, int bn,
                            u16* As, u16* Bs, f32x4 acc[4][4]) {
  const int tid = threadIdx.x;
  const int w = tid >> 6, l = tid & 63;
  const int lr = l & 15, lg = l >> 4;
  const int wr = (w >> 1) * 64, wc = (w & 1) * 64;

  for (int i = 0; i < 4; ++i)
    for (int j = 0; j < 4; ++j) acc[i][j] = (f32x4){0.f, 0.f, 0.f, 0.f};

  const int c0 = 2 * w, c1 = 2 * w + 1;
  const u16* gA0 = A + (size_t)(bm * 128 + c0 * 16 + (l >> 2)) * 1024 + (l & 3) * 8;
  const u16* gA1 = A + (size_t)(bm * 128 + c1 * 16 + (l >> 2)) * 1024 + (l & 3) * 8;
  const u16* gB0 = Bm + (size_t)(bn * 128 + c0 * 16 + (l >> 2)) * 1024 + (l & 3) * 8;
  const u16* gB1 = Bm + (size_t)(bn * 128 + c1 * 16 + (l >> 2)) * 1024 + (l & 3) * 8;
  const int sA0 = c0 * 512, sA1 = c1 * 512;

  int aoff[4], boff[4];
#pragma unroll
  for (int mi = 0; mi < 4; ++mi) aoff[mi] = (wr + mi * 16 + lr) * 32 + lg * 8;
#pragma unroll
  for (int nj = 0; nj < 4; ++nj) boff[nj] = (wc + nj * 16 + lr) * 32 + lg * 8;

  load_lds16(gA0, As + sA0);
  load_lds16(gA1, As + sA1);
  load_lds16(gB0, Bs + sA0);
  load_lds16(gB1, Bs + sA1);
  __syncthreads();

  int cur = 0;
  for (int k0 = 0; k0 < 1024; k0 += 32) {
    const int nxt = cur ^ 1;
    if (k0 + 32 < 1024) {
      load_lds16(gA0 + k0 + 32, As + nxt * 4096 + sA0);
      load_lds16(gA1 + k0 + 32, As + nxt * 4096 + sA1);
      load_lds16(gB0 + k0 + 32, Bs + nxt * 4096 + sA0);
      load_lds16(gB1 + k0 + 32, Bs + nxt * 4096 + sA1);
    }
    const u16* Ac = As + cur * 4096;
    const u16* Bc = Bs + cur * 4096;
    bf16x8 af[4], bff[4];
#pragma unroll
    for (int mi = 0; mi < 4; ++mi) af[mi] = lds_frag(&Ac[aoff[mi]]);
#pragma unroll
    for (int nj = 0; nj < 4; ++nj) bff[nj] = lds_frag(&Bc[boff[nj]]);
#pragma unroll
    for (int mi = 0; mi < 4; ++mi)
#pragma unroll
      for (int nj = 0; nj < 4; ++nj)
        acc[mi][nj] = mfma16(af[mi], bff[nj], acc[mi][nj]);
    __syncthreads();
    cur = nxt;
  }
}

// ---------- output projection ----------
__global__ __launch_bounds__(256) void outproj_kernel(const u16* O,
                                                      const u16* Wo,
                                                      const float* bo,
                                                      float* out) {
  __shared__ __align__(16) u16 As[2 * 128 * 32];
  __shared__ __align__(16) u16 Bs[2 * 128 * 32];
  f32x4 acc[4][4];
  gemm_core_1024_db(O, Wo, blockIdx.x, blockIdx.y, As, Bs, acc);

  const int tid = threadIdx.x;
  const int w = tid >> 6, l = tid & 63;
  const int lr = l & 15, lg = l >> 4;
  const int wr = (w >> 1) * 64, wc = (w & 1) * 64;
#pragma unroll
  for (int nj = 0; nj < 4; ++nj) {
    const int col = blockIdx.y * 128 + wc + nj * 16 + lr;
    const float bb = bo[col];
#pragma unroll
    for (int mi = 0; mi < 4; ++mi) {
      const int m0 = blockIdx.x * 128 + wr + mi * 16 + lg * 4;
#pragma unroll
      for (int r = 0; r < 4; ++r)
        out[(size_t)(m0 + r) * 1024 + col] = acc[mi][nj][r] + bb;
    }
  }
}

// ---------- flash attention v7n: natural-layout Q/K ([B,S,H*64]) ------------
#define LDPK 72
#define NT 32  // 2048 / 64
__global__ __launch_bounds__(512) void attn_kernel(const u16* Qn, const u16* Kn,
                                                   const u16* Vt, u16* Ob) {
  __shared__ __align__(16) u16 Kl[2][64 * LDPK];
  __shared__ __align__(16) u16 Vl[2][64 * LDPK];

  const int tid = threadIdx.x, w = tid >> 6, l = tid & 63;
  const int q = l & 31, hi = l >> 5;
  const int bh = blockIdx.y;
  const int b2 = bh >> 4, h = bh & 15;
  const int q0 = blockIdx.x * 256 + w * 32;
  const u16* Qh = Qn + (size_t)b2 * 2048 * 1024 + h * 64;
  const u16* Kh = Kn + (size_t)b2 * 2048 * 1024 + h * 64;
  const u16* Vh = Vt + (size_t)bh * 64 * 2048;

  const float SC2 = 0.1803368801f;  // 0.125 * log2(e)

  bf16x8 qf[4];
#pragma unroll
  for (int ds = 0; ds < 4; ++ds)
    qf[ds] = *(const bf16x8*)&Qh[(size_t)(q0 + q) * 1024 + ds * 16 + hi * 8];

  f32x16 o0 = zero16(), o1 = zero16();
  float m = -1.0e30f, ln = 0.f;

  const int srow = tid >> 3, g0 = tid & 7;

  int koff[2][4], voff[2][4];
#pragma unroll
  for (int kb = 0; kb < 2; ++kb)
#pragma unroll
    for (int ds = 0; ds < 4; ++ds)
      koff[kb][ds] = (kb * 32 + q) * LDPK + ds * 16 + hi * 8;
#pragma unroll
  for (int db = 0; db < 2; ++db)
#pragma unroll
    for (int ks = 0; ks < 4; ++ks)
      voff[db][ks] = (db * 32 + q) * LDPK + ks * 16 + hi * 8;

  bf16x8 kv = *(const bf16x8*)&Kh[(size_t)srow * 1024 + g0 * 8];
  bf16x8 vv = *(const bf16x8*)&Vh[(size_t)srow * 2048 + g0 * 8];
  *(bf16x8*)&Kl[0][srow * LDPK + g0 * 8] = kv;
  *(bf16x8*)&Vl[0][srow * LDPK + g0 * 8] = vv;
  kv = *(const bf16x8*)&Kh[(size_t)(64 + srow) * 1024 + g0 * 8];
  vv = *(const bf16x8*)&Vh[(size_t)srow * 2048 + 64 + g0 * 8];
  const u16* gk = Kh + (size_t)(2 * 64 + srow) * 1024 + g0 * 8;
  const u16* gv = Vh + (size_t)srow * 2048 + 2 * 64 + g0 * 8;
  __syncthreads();

  for (int kt = 0; kt < NT; ++kt) {
    const int cur = kt & 1;
    const u16* Kc = Kl[cur];
    const u16* Vc = Vl[cur];

    f32x16 c0 = zero16(), c1 = zero16();
    __builtin_amdgcn_s_setprio(1);
#pragma unroll
    for (int ds = 0; ds < 4; ++ds)
      c0 = mfma32(lds_frag(&Kc[koff[0][ds]]), qf[ds], c0);
#pragma unroll
    for (int ds = 0; ds < 4; ++ds)
      c1 = mfma32(lds_frag(&Kc[koff[1][ds]]), qf[ds], c1);
    __builtin_amdgcn_s_setprio(0);

    float tm[16];
#pragma unroll
    for (int r = 0; r < 16; ++r) tm[r] = fmaxf(c0[r], c1[r]);
    {
      const float m0_ = max3f(tm[0], tm[1], tm[2]);
      const float m1_ = max3f(tm[3], tm[4], tm[5]);
      const float m2_ = max3f(tm[6], tm[7], tm[8]);
      const float m3_ = max3f(tm[9], tm[10], tm[11]);
      const float m4_ = max3f(tm[12], tm[13], tm[14]);
      const float a_ = max3f(m0_, m1_, m2_);
      const float b_ = max3f(m3_, m4_, tm[15]);
      tm[0] = fmaxf(a_, b_);
    }
    const float mx = fmaxf(tm[0], partner_f(tm[0]));
    if (!__all(mx - m <= 64.0f)) {
      const float mnew = fmaxf(m, mx);
      const float a = exp2_hw((m - mnew) * SC2);
      m = mnew;
#pragma unroll
      for (int r = 0; r < 16; ++r) { o0[r] *= a; o1[r] *= a; }
      ln *= a;
    }
    const float m2 = m * SC2;
    float p0[16], p1[16];
#pragma unroll
    for (int r = 0; r < 16; ++r) {
      p0[r] = exp2_hw(__builtin_fmaf(c0[r], SC2, -m2));
      p1[r] = exp2_hw(__builtin_fmaf(c1[r], SC2, -m2));
    }
    float ts[16];
#pragma unroll
    for (int r = 0; r < 16; ++r) ts[r] = p0[r] + p1[r];
#pragma unroll
    for (int s = 8; s > 0; s >>= 1)
#pragma unroll
      for (int r = 0; r < s; ++r) ts[r] += ts[r + s];
    ln += ts[0] + partner_f(ts[0]);

    if (kt + 1 < NT) {
      *(bf16x8*)&Kl[cur ^ 1][srow * LDPK + g0 * 8] = kv;
      *(bf16x8*)&Vl[cur ^ 1][srow * LDPK + g0 * 8] = vv;
    }
    if (kt + 2 < NT) {
      kv = *(const bf16x8*)gk;
      vv = *(const bf16x8*)gv;
      gk += 64 * 1024; gv += 64;
    }

    uint32_t wv[16];
#pragma unroll
    for (int i = 0; i < 8; ++i) {
      wv[i]     = cvtpk(p0[2 * i], p0[2 * i + 1]);
      wv[8 + i] = cvtpk(p1[2 * i], p1[2 * i + 1]);
    }
    bf16x8 pa[4];
#pragma unroll
    for (int ks = 0; ks < 4; ++ks) {
      const int base = (ks >> 1) * 8 + 4 * (ks & 1);
      uint32_t x0 = wv[base],     y0 = wv[base + 2];
      uint32_t x1 = wv[base + 1], y1 = wv[base + 3];
      pswap_asm(x0, y0);
      pswap_asm(x1, y1);
      union { uint32_t u[4]; bf16x8 v; } cvt;
      cvt.u[0] = x0; cvt.u[1] = x1; cvt.u[2] = y0; cvt.u[3] = y1;
      pa[ks] = cvt.v;
    }

    __builtin_amdgcn_s_setprio(1);
#pragma unroll
    for (int ks = 0; ks < 4; ++ks)
      o0 = mfma32(lds_frag(&Vc[voff[0][ks]]), pa[ks], o0);
#pragma unroll
    for (int ks = 0; ks < 4; ++ks)
      o1 = mfma32(lds_frag(&Vc[voff[1][ks]]), pa[ks], o1);
    __builtin_amdgcn_s_setprio(0);

    __syncthreads();
  }

  const float inv = 1.0f / ln;
  u16* orow = Ob + ((size_t)(b2 * 2048 + q0 + q)) * 1024 + h * 64;
#pragma unroll
  for (int g = 0; g < 4; ++g) {
    u16x4 pk;
    pk.x = f2bf(o0[4 * g + 0] * inv);
    pk.y = f2bf(o0[4 * g + 1] * inv);
    pk.z = f2bf(o0[4 * g + 2] * inv);
    pk.w = f2bf(o0[4 * g + 3] * inv);
    *(u16x4*)&orow[8 * g + 4 * hi] = pk;
  }
#pragma unroll
  for (int g = 0; g < 4; ++g) {
    u16x4 pk;
    pk.x = f2bf(o1[4 * g + 0] * inv);
    pk.y = f2bf(o1[4 * g + 1] * inv);
    pk.z = f2bf(o1[4 * g + 2] * inv);
    pk.w = f2bf(o1[4 * g + 3] * inv);
    *(u16x4*)&orow[32 + 8 * g + 4 * hi] = pk;
  }
}

// ---------- launcher ----------
extern "C" void kernel_launch(void* const* d_in, const int* in_sizes, int n_in,
                              void* d_out, int out_size, void* d_ws,
                              size_t ws_size, hipStream_t stream) {
  const float* q  = (const float*)d_in[0];
  const float* k  = (const float*)d_in[1];
  const float* v  = (const float*)d_in[2];
  const float* Wq = (const float*)d_in[3];
  const float* bq = (const float*)d_in[4];
  const float* Wk = (const float*)d_in[5];
  const float* bk = (const float*)d_in[6];
  const float* Wv = (const float*)d_in[7];
  const float* bv = (const float*)d_in[8];
  const float* Wo = (const float*)d_in[9];
  const float* bo = (const float*)d_in[10];
  float* out = (float*)d_out;

  u16* ws = (u16*)d_ws;
  u16* Wqb = ws;              // [1024,1024] bf16 x4
  u16* Wkb = Wqb + NW;
  u16* Wvb = Wkb + NW;
  u16* Wob = Wvb + NW;
  u16* Qn  = Wob + NW;        // [B,S,1024] natural
  u16* Kn  = Qn + NBIG;       // [B,S,1024] natural
  u16* Vt  = Kn + NBIG;       // [B,H,64,S] transposed
  u16* O   = Vt + NBIG;       // [B,S,H*64] attn output (bf16)

  cvt_kernel<<<dim3(1024, 4, 1), 256, 0, stream>>>(Wq, Wk, Wv, Wo, Wqb, Wkb,
                                                   Wvb, Wob);
  proj_kernel<<<dim3(64, 4, 3), 512, 0, stream>>>(q, k, v, Wqb, Wkb, Wvb, bq,
                                                  bk, bv, Qn, Kn, Vt);
  attn_kernel<<<dim3(8, 64, 1), 512, 0, stream>>>(Qn, Kn, Vt, O);
  outproj_kernel<<<dim3(64, 8, 1), 256, 0, stream>>>(O, Wob, bo, out);
}